// Round 4
// baseline (640.292 us; speedup 1.0000x reference)
//
#include <hip/hip_runtime.h>
#include <hip/hip_bf16.h>

// Viterbi CRF decode: B=512, T=512, K=64.
// Round 6: one wave per batch, transition column PINNED in 64 VGPRs.
// History: r3/r4 (tc[] plain array) -> compiler rematerialized the 64
// loop-invariant loads from GLOBAL each step (VGPR=48, 1760 cy/step of L2
// latency, 1 wave/SIMD = no TLP). r5 (LDS) -> still re-read 64 values/step
// from LDS in ~8 batches with lgkmcnt waits (~960 cy/step exposed, VGPR=72,
// VALUBusy 38%). Fix: after the one-time load, each tc[i] passes through
// `asm volatile("" : "+v")` -- asm outputs cannot be rematerialized, so the
// allocator must keep all 64 live in VGPRs (~110 total, fine at 1 wave/EU).
// Per-step loop touches no memory except prefetched emission row, uniform
// mask s_load, and the 64B hist store: ~380 VALU ops, ~760 cy/step.
// Argmax: 8 ascending strict-> chains of 8 (ILP=8), merged low-group-first
// => jnp.argmax first-index tie-break. FP association (score + trans) + emit
// kept exactly -> bitwise-identical scores. Backtrace unchanged (verified).
// Workspace: hist uint8 [B][512][K] = 16.78 MB (row 511 pad) + best_last[B].

#define TT 512
#define BB 512
#define KK 64

#define NEG_INF (-3.402823466e38f)

__global__ __launch_bounds__(64, 1) void viterbi_fwd(
    const float* __restrict__ emissions,   // [B,T,K]
    const int* __restrict__ attn_mask,     // [B,T]
    const float* __restrict__ start_t,     // [K]
    const float* __restrict__ end_t,       // [K]
    const float* __restrict__ trans,       // [K,K]
    unsigned char* __restrict__ hist,      // [B,512,K] (row 511 pad)
    int* __restrict__ best_last)           // [B]
{
    const int b = blockIdx.x;
    const int j = threadIdx.x & 63;

    // one-time load of this lane's transition column: tc[i] = trans[i][j]
    float tc[KK];
#pragma unroll
    for (int i = 0; i < KK; ++i) tc[i] = trans[i * KK + j];
    // pin into VGPRs: asm outputs are not rematerializable, so the
    // allocator must keep all 64 live across the t-loop instead of
    // re-loading them each step (the r3-r5 failure mode).
#pragma unroll
    for (int i = 0; i < KK; ++i) asm volatile("" : "+v"(tc[i]));

    const float* eb = emissions + (size_t)b * TT * KK;
    const int*   mb = attn_mask + (size_t)b * TT;
    unsigned char* hb = hist + (size_t)b * TT * KK;

    // score vector lives lane-distributed: lane j holds score[j]
    float score = start_t[j] + eb[j];

    // 2-deep prefetch rings for emissions row and mask
    float e0 = eb[KK + j];
    float e1 = eb[2 * KK + j];
    int   m0 = mb[1];
    int   m1 = mb[2];

    for (int t = 1; t < TT; ++t) {
        float e = e0; e0 = e1;
        int   m = m0; m0 = m1;
        int tn = (t + 2 < TT) ? (t + 2) : (TT - 1);
        e1 = eb[(size_t)tn * KK + j];
        m1 = mb[tn];

        // 8 groups of 8 prev-tags, ascending strict-> chains (first-index
        // tie rule), then ascending merge of group winners.
        float gv[8];
        int   gi[8];
#pragma unroll
        for (int g = 0; g < 8; ++g) {
            const int base = g * 8;
            float s0 = __uint_as_float(
                __builtin_amdgcn_readlane(__float_as_uint(score), base));
            float bv = (s0 + tc[base]) + e;
            int   bi = base;
#pragma unroll
            for (int q = 1; q < 8; ++q) {
                float s = __uint_as_float(
                    __builtin_amdgcn_readlane(__float_as_uint(score), base + q));
                float c = (s + tc[base + q]) + e;
                if (c > bv) { bv = c; bi = base + q; }
            }
            gv[g] = bv;
            gi[g] = bi;
        }
        float best = gv[0];
        int   bi   = gi[0];
#pragma unroll
        for (int g = 1; g < 8; ++g)
            if (gv[g] > best) { best = gv[g]; bi = gi[g]; }

        // history recorded unconditionally (reference scan records idx
        // regardless of mask; mask applied in backtrace)
        hb[(size_t)(t - 1) * KK + j] = (unsigned char)bi;
        // freeze past sequence end
        score = m ? best : score;
    }

    // final: add end transitions, argmax over tags (first-index ties)
    float fin = score + end_t[j];
    __shared__ float sv[KK];
    sv[j] = fin;
    __syncthreads();
    if (j == 0) {
        float bv = sv[0];
        int   bt = 0;
#pragma unroll
        for (int k = 1; k < KK; ++k) {
            float v = sv[k];
            if (v > bv) { bv = v; bt = k; }
        }
        best_last[b] = bt;
    }
}

__global__ __launch_bounds__(64) void viterbi_bt(
    const unsigned char* __restrict__ hist,  // [B,512,K]
    const int* __restrict__ attn_mask,       // [B,T]
    const int* __restrict__ best_last,       // [B]
    int* __restrict__ out)                   // [B,T] int32
{
    const int b = blockIdx.x;
    const int l = threadIdx.x;
    __shared__ int path[TT];

    const unsigned int* hw = (const unsigned int*)(hist + (size_t)b * TT * KK);
    const int* mb = attn_mask + (size_t)b * TT;

    int tag = best_last[b];          // broadcast (uniform on all lanes)
    if (l == 0) path[TT - 1] = tag;

    unsigned int dwA[16], dwB[16];
    int mA, mB;

    auto loadChunk = [&](int c, unsigned int (&dw)[16], int& mreg) {
#pragma unroll
        for (int q4 = 0; q4 < 16; ++q4)
            dw[q4] = hw[c * 1024 + q4 * 64 + l];   // 4 rows per wave-load
        int midx = c * 64 + l + 1;
        if (midx > TT - 1) midx = TT - 1;
        mreg = mb[midx];                            // lane l: mask[b][c*64+l+1]
    };
    auto procChunk = [&](int c, unsigned int (&dw)[16], int mreg) {
#pragma unroll
        for (int q = 63; q >= 0; --q) {
            int r = c * 64 + q;
            if (r < TT - 1) {
                // byte hist[r][tag]: local dword q*16+(tag>>2)
                unsigned int d = __shfl(dw[q >> 2], ((q & 3) << 4) + (tag >> 2));
                int pv = (int)((d >> ((tag & 3) << 3)) & 0xFFu);
                int m  = __shfl(mreg, q);
                tag = m ? pv : tag;
                if (l == 0) path[r] = tag;
            }
        }
    };

    loadChunk(7, dwA, mA);
    for (int c = 7; c >= 1; c -= 2) {
        loadChunk(c - 1, dwB, mB);
        procChunk(c, dwA, mA);
        if (c >= 2) loadChunk(c - 2, dwA, mA);
        procChunk(c - 1, dwB, mB);
    }

    __syncthreads();
#pragma unroll
    for (int cc = 0; cc < 8; ++cc)
        out[(size_t)b * TT + cc * 64 + l] = path[cc * 64 + l];
}

extern "C" void kernel_launch(void* const* d_in, const int* in_sizes, int n_in,
                              void* d_out, int out_size, void* d_ws, size_t ws_size,
                              hipStream_t stream) {
    const float* emissions = (const float*)d_in[0];
    const int* attn_mask   = (const int*)d_in[1];
    const float* start_t   = (const float*)d_in[2];
    const float* end_t     = (const float*)d_in[3];
    const float* trans     = (const float*)d_in[4];
    int* out = (int*)d_out;

    unsigned char* hist = (unsigned char*)d_ws;
    int* best_last = (int*)((char*)d_ws + (size_t)BB * TT * KK);

    viterbi_fwd<<<BB, KK, 0, stream>>>(emissions, attn_mask, start_t, end_t,
                                       trans, hist, best_last);
    viterbi_bt<<<BB, KK, 0, stream>>>(hist, attn_mask, best_last, out);
}

// Round 5
// 507.868 us; speedup vs baseline: 1.2607x; 1.2607x over previous
//
#include <hip/hip_runtime.h>
#include <hip/hip_bf16.h>

// Viterbi CRF decode: B=512, T=512, K=64.
// Round 7: one wave per batch; transitions re-read from LDS each step as
// 16x ds_read_b128 from a TRANSPOSED, PADDED layout, software-pipelined.
// History of the residency war: r3/r4 (plain tc[64]) and r6 (asm-pinned
// tc[64]) -> compiler re-loads trans from GLOBAL every step (VGPR=48,
// identical counters; ~1760cy/step exposed L2 latency, 1 wave/SIMD = no
// TLP). r5 (row-major LDS, 64x ds_read_b32/step) -> ~8 batched lgkmcnt
// waits, 960cy/step exposed (400us, VALUBusy 38%). The backend refuses to
// keep 64 floats/lane live across the loop, full stop.
// This round accepts the re-read but makes it cheap: ldsT[j][i]=T[i][j],
// row stride 68 floats (272B: 16B-aligned for b128; padding avoids the
// 16-way stride-64 bank pattern; 8-deep is the inherent b128 floor).
// 16 wide reads, 2-group-deep ring (4 quads in flight) overlaps LDS
// latency with readlane/add/cmp of the previous group. An asm pin on a
// zero OFFSET (not the pointer -- preserves addrspace(3) so reads stay
// ds_read_b128 with immediate offsets) defeats LICM so the reads can't be
// hoisted back into the spill pathology.
// Argmax: 8 ascending strict-> chains of 8, merged low-group-first =>
// jnp.argmax first-index tie-break. FP association (s+t)+e exact ->
// bitwise-identical scores. Backtrace unchanged (verified).
// Workspace: hist uint8 [B][512][K] = 16.78 MB (row 511 pad) + best_last[B].

#define TT 512
#define BB 512
#define KK 64
#define RS 68   // padded row stride (floats) for transposed trans in LDS

#define NEG_INF (-3.402823466e38f)

__global__ __launch_bounds__(64) void viterbi_fwd(
    const float* __restrict__ emissions,   // [B,T,K]
    const int* __restrict__ attn_mask,     // [B,T]
    const float* __restrict__ start_t,     // [K]
    const float* __restrict__ end_t,       // [K]
    const float* __restrict__ trans,       // [K,K]
    unsigned char* __restrict__ hist,      // [B,512,K] (row 511 pad)
    int* __restrict__ best_last)           // [B]
{
    const int b = blockIdx.x;
    const int j = threadIdx.x & 63;

    // transposed + padded transitions: ldsT[j*RS + i] = trans[i][j]
    __shared__ __align__(16) float ldsT[KK * RS];   // 17408 B
    __shared__ float sv[KK];

#pragma unroll 4
    for (int i = 0; i < KK; ++i)
        ldsT[j * RS + i] = trans[i * KK + j];   // coalesced read, strided write
    __syncthreads();

    const float* row = &ldsT[j * RS];

    const float* eb = emissions + (size_t)b * TT * KK;
    const int*   mb = attn_mask + (size_t)b * TT;
    unsigned char* hb = hist + (size_t)b * TT * KK;

    // score vector lives lane-distributed: lane j holds score[j]
    float score = start_t[j] + eb[j];

    // 2-deep prefetch rings for emissions row and mask
    float e0 = eb[KK + j];
    float e1 = eb[2 * KK + j];
    int   m0 = mb[1];
    int   m1 = mb[2];

    for (int t = 1; t < TT; ++t) {
        float e = e0; e0 = e1;
        int   m = m0; m0 = m1;
        int tn = (t + 2 < TT) ? (t + 2) : (TT - 1);
        e1 = eb[(size_t)tn * KK + j];
        m1 = mb[tn];

        // opaque zero offset: loop-variant address -> no LICM of ds reads,
        // but provenance (addrspace 3) kept -> ds_read_b128 + imm offsets.
        unsigned off = 0;
        asm volatile("" : "+v"(off));
        const float* rb = row + off;

#define LDQ(q) (*(const float4*)(rb + 4 * (q)))
#define RL(i)  __uint_as_float(__builtin_amdgcn_readlane(__float_as_uint(score), (i)))

        float gv[8];
        int   gi[8];

        // ring: qa = quads for current group, qb = next group
        float4 qa0 = LDQ(0), qa1 = LDQ(1), qb0 = LDQ(2), qb1 = LDQ(3);
#pragma unroll
        for (int g = 0; g < 8; ++g) {
            float4 p0 = qa0, p1 = qa1;            // dead unless g<6
            if (g < 6) { p0 = LDQ(2 * g + 4); p1 = LDQ(2 * g + 5); }

            const int base = 8 * g;
            // 8 candidates, ascending strict-> chain (first-index ties)
            float bv = (RL(base + 0) + qa0.x) + e; int bi = base;
            float c;
            c = (RL(base + 1) + qa0.y) + e; if (c > bv) { bv = c; bi = base + 1; }
            c = (RL(base + 2) + qa0.z) + e; if (c > bv) { bv = c; bi = base + 2; }
            c = (RL(base + 3) + qa0.w) + e; if (c > bv) { bv = c; bi = base + 3; }
            c = (RL(base + 4) + qa1.x) + e; if (c > bv) { bv = c; bi = base + 4; }
            c = (RL(base + 5) + qa1.y) + e; if (c > bv) { bv = c; bi = base + 5; }
            c = (RL(base + 6) + qa1.z) + e; if (c > bv) { bv = c; bi = base + 6; }
            c = (RL(base + 7) + qa1.w) + e; if (c > bv) { bv = c; bi = base + 7; }
            gv[g] = bv;
            gi[g] = bi;

            qa0 = qb0; qa1 = qb1; qb0 = p0; qb1 = p1;
        }

        // merge group winners ascending (first-index tie rule preserved)
        float best = gv[0];
        int   bi   = gi[0];
#pragma unroll
        for (int g = 1; g < 8; ++g)
            if (gv[g] > best) { best = gv[g]; bi = gi[g]; }

#undef LDQ
#undef RL

        // history recorded unconditionally (mask applied in backtrace)
        hb[(size_t)(t - 1) * KK + j] = (unsigned char)bi;
        // freeze past sequence end
        score = m ? best : score;
    }

    // final: add end transitions, argmax over tags (first-index ties)
    float fin = score + end_t[j];
    sv[j] = fin;
    __syncthreads();
    if (j == 0) {
        float bv = sv[0];
        int   bt = 0;
#pragma unroll
        for (int k = 1; k < KK; ++k) {
            float v = sv[k];
            if (v > bv) { bv = v; bt = k; }
        }
        best_last[b] = bt;
    }
}

__global__ __launch_bounds__(64) void viterbi_bt(
    const unsigned char* __restrict__ hist,  // [B,512,K]
    const int* __restrict__ attn_mask,       // [B,T]
    const int* __restrict__ best_last,       // [B]
    int* __restrict__ out)                   // [B,T] int32
{
    const int b = blockIdx.x;
    const int l = threadIdx.x;
    __shared__ int path[TT];

    const unsigned int* hw = (const unsigned int*)(hist + (size_t)b * TT * KK);
    const int* mb = attn_mask + (size_t)b * TT;

    int tag = best_last[b];          // broadcast (uniform on all lanes)
    if (l == 0) path[TT - 1] = tag;

    unsigned int dwA[16], dwB[16];
    int mA, mB;

    auto loadChunk = [&](int c, unsigned int (&dw)[16], int& mreg) {
#pragma unroll
        for (int q4 = 0; q4 < 16; ++q4)
            dw[q4] = hw[c * 1024 + q4 * 64 + l];   // 4 rows per wave-load
        int midx = c * 64 + l + 1;
        if (midx > TT - 1) midx = TT - 1;
        mreg = mb[midx];                            // lane l: mask[b][c*64+l+1]
    };
    auto procChunk = [&](int c, unsigned int (&dw)[16], int mreg) {
#pragma unroll
        for (int q = 63; q >= 0; --q) {
            int r = c * 64 + q;
            if (r < TT - 1) {
                // byte hist[r][tag]: local dword q*16+(tag>>2)
                unsigned int d = __shfl(dw[q >> 2], ((q & 3) << 4) + (tag >> 2));
                int pv = (int)((d >> ((tag & 3) << 3)) & 0xFFu);
                int m  = __shfl(mreg, q);
                tag = m ? pv : tag;
                if (l == 0) path[r] = tag;
            }
        }
    };

    loadChunk(7, dwA, mA);
    for (int c = 7; c >= 1; c -= 2) {
        loadChunk(c - 1, dwB, mB);
        procChunk(c, dwA, mA);
        if (c >= 2) loadChunk(c - 2, dwA, mA);
        procChunk(c - 1, dwB, mB);
    }

    __syncthreads();
#pragma unroll
    for (int cc = 0; cc < 8; ++cc)
        out[(size_t)b * TT + cc * 64 + l] = path[cc * 64 + l];
}

extern "C" void kernel_launch(void* const* d_in, const int* in_sizes, int n_in,
                              void* d_out, int out_size, void* d_ws, size_t ws_size,
                              hipStream_t stream) {
    const float* emissions = (const float*)d_in[0];
    const int* attn_mask   = (const int*)d_in[1];
    const float* start_t   = (const float*)d_in[2];
    const float* end_t     = (const float*)d_in[3];
    const float* trans     = (const float*)d_in[4];
    int* out = (int*)d_out;

    unsigned char* hist = (unsigned char*)d_ws;
    int* best_last = (int*)((char*)d_ws + (size_t)BB * TT * KK);

    viterbi_fwd<<<BB, KK, 0, stream>>>(emissions, attn_mask, start_t, end_t,
                                       trans, hist, best_last);
    viterbi_bt<<<BB, KK, 0, stream>>>(hist, attn_mask, best_last, out);
}

// Round 6
// 504.584 us; speedup vs baseline: 1.2690x; 1.0065x over previous
//
#include <hip/hip_runtime.h>
#include <hip/hip_bf16.h>

// Viterbi CRF decode: B=512, T=512, K=64.
// Round 8: one wave per batch; score broadcast via ds_bpermute (uniform
// index = HW broadcast) instead of v_readlane.
// Stall history: r3-r7 all plateau at 400-530us with VALUBusy 29-38%.
// r5 (64x ds_read_b32) vs r7 (16x ds_read_b128, pipelined) differ <3% ->
// LDS read latency is NOT the bottleneck. The invariant across all slow
// variants: 64 v_readlane per step, each feeding a dependent v_add through
// an SGPR. v_readlane writes an SGPR; the consuming VALU op hits the
// VALU->SGPR->VALU hazard (~wait states), and at 1 wave/SIMD there is no
// TLP to absorb ~64 x ~18cy of bubbles = the observed ~1190cy/step stall.
// Fix: __builtin_amdgcn_ds_bpermute(4*i, score) -- all lanes read lane i
// (broadcast, conflict-free), result lands in a VGPR via the LDS permute
// network, 64 independent ops that pipeline under the compare tree.
// Everything else identical to r7: tc via 16x ds_read_b128 from padded
// transposed LDS (off-pin defeats LICM), FP association (s+tc)+e exact,
// 8 ascending strict-> chains of 8 merged low-group-first => jnp.argmax
// first-index tie-break. Backtrace unchanged (verified).
// Workspace: hist uint8 [B][512][K] = 16.78 MB (row 511 pad) + best_last[B].

#define TT 512
#define BB 512
#define KK 64
#define RS 68   // padded row stride (floats) for transposed trans in LDS

#define NEG_INF (-3.402823466e38f)

__global__ __launch_bounds__(64) void viterbi_fwd(
    const float* __restrict__ emissions,   // [B,T,K]
    const int* __restrict__ attn_mask,     // [B,T]
    const float* __restrict__ start_t,     // [K]
    const float* __restrict__ end_t,       // [K]
    const float* __restrict__ trans,       // [K,K]
    unsigned char* __restrict__ hist,      // [B,512,K] (row 511 pad)
    int* __restrict__ best_last)           // [B]
{
    const int b = blockIdx.x;
    const int j = threadIdx.x & 63;

    // transposed + padded transitions: ldsT[j*RS + i] = trans[i][j]
    __shared__ __align__(16) float ldsT[KK * RS];   // 17408 B
    __shared__ float sv[KK];

#pragma unroll 4
    for (int i = 0; i < KK; ++i)
        ldsT[j * RS + i] = trans[i * KK + j];   // coalesced read, strided write
    __syncthreads();

    const float* row = &ldsT[j * RS];

    const float* eb = emissions + (size_t)b * TT * KK;
    const int*   mb = attn_mask + (size_t)b * TT;
    unsigned char* hb = hist + (size_t)b * TT * KK;

    // score vector lives lane-distributed: lane j holds score[j]
    float score = start_t[j] + eb[j];

    // 2-deep prefetch rings for emissions row and mask
    float e0 = eb[KK + j];
    float e1 = eb[2 * KK + j];
    int   m0 = mb[1];
    int   m1 = mb[2];

    for (int t = 1; t < TT; ++t) {
        float e = e0; e0 = e1;
        int   m = m0; m0 = m1;
        int tn = (t + 2 < TT) ? (t + 2) : (TT - 1);
        e1 = eb[(size_t)tn * KK + j];
        m1 = mb[tn];

        // opaque zero offset: loop-variant address -> no LICM of ds reads,
        // but provenance (addrspace 3) kept -> ds_read_b128 + imm offsets.
        unsigned off = 0;
        asm volatile("" : "+v"(off));
        const float* rb = row + off;

#define LDQ(q) (*(const float4*)(rb + 4 * (q)))
        // broadcast score[i] to all lanes via LDS permute network (VGPR
        // result, no SGPR hazard; uniform index = conflict-free broadcast)
#define BC(i)  __uint_as_float(__builtin_amdgcn_ds_bpermute(4 * (i), __float_as_uint(score)))

        float gv[8];
        int   gi[8];

        // ring: qa = quads for current group, qb = next group
        float4 qa0 = LDQ(0), qa1 = LDQ(1), qb0 = LDQ(2), qb1 = LDQ(3);
#pragma unroll
        for (int g = 0; g < 8; ++g) {
            float4 p0 = qa0, p1 = qa1;            // dead unless g<6
            if (g < 6) { p0 = LDQ(2 * g + 4); p1 = LDQ(2 * g + 5); }

            const int base = 8 * g;
            // 8 candidates, ascending strict-> chain (first-index ties)
            float bv = (BC(base + 0) + qa0.x) + e; int bi = base;
            float c;
            c = (BC(base + 1) + qa0.y) + e; if (c > bv) { bv = c; bi = base + 1; }
            c = (BC(base + 2) + qa0.z) + e; if (c > bv) { bv = c; bi = base + 2; }
            c = (BC(base + 3) + qa0.w) + e; if (c > bv) { bv = c; bi = base + 3; }
            c = (BC(base + 4) + qa1.x) + e; if (c > bv) { bv = c; bi = base + 4; }
            c = (BC(base + 5) + qa1.y) + e; if (c > bv) { bv = c; bi = base + 5; }
            c = (BC(base + 6) + qa1.z) + e; if (c > bv) { bv = c; bi = base + 6; }
            c = (BC(base + 7) + qa1.w) + e; if (c > bv) { bv = c; bi = base + 7; }
            gv[g] = bv;
            gi[g] = bi;

            qa0 = qb0; qa1 = qb1; qb0 = p0; qb1 = p1;
        }

        // merge group winners ascending (first-index tie rule preserved)
        float best = gv[0];
        int   bi   = gi[0];
#pragma unroll
        for (int g = 1; g < 8; ++g)
            if (gv[g] > best) { best = gv[g]; bi = gi[g]; }

#undef LDQ
#undef BC

        // history recorded unconditionally (mask applied in backtrace)
        hb[(size_t)(t - 1) * KK + j] = (unsigned char)bi;
        // freeze past sequence end
        score = m ? best : score;
    }

    // final: add end transitions, argmax over tags (first-index ties)
    float fin = score + end_t[j];
    sv[j] = fin;
    __syncthreads();
    if (j == 0) {
        float bv = sv[0];
        int   bt = 0;
#pragma unroll
        for (int k = 1; k < KK; ++k) {
            float v = sv[k];
            if (v > bv) { bv = v; bt = k; }
        }
        best_last[b] = bt;
    }
}

__global__ __launch_bounds__(64) void viterbi_bt(
    const unsigned char* __restrict__ hist,  // [B,512,K]
    const int* __restrict__ attn_mask,       // [B,T]
    const int* __restrict__ best_last,       // [B]
    int* __restrict__ out)                   // [B,T] int32
{
    const int b = blockIdx.x;
    const int l = threadIdx.x;
    __shared__ int path[TT];

    const unsigned int* hw = (const unsigned int*)(hist + (size_t)b * TT * KK);
    const int* mb = attn_mask + (size_t)b * TT;

    int tag = best_last[b];          // broadcast (uniform on all lanes)
    if (l == 0) path[TT - 1] = tag;

    unsigned int dwA[16], dwB[16];
    int mA, mB;

    auto loadChunk = [&](int c, unsigned int (&dw)[16], int& mreg) {
#pragma unroll
        for (int q4 = 0; q4 < 16; ++q4)
            dw[q4] = hw[c * 1024 + q4 * 64 + l];   // 4 rows per wave-load
        int midx = c * 64 + l + 1;
        if (midx > TT - 1) midx = TT - 1;
        mreg = mb[midx];                            // lane l: mask[b][c*64+l+1]
    };
    auto procChunk = [&](int c, unsigned int (&dw)[16], int mreg) {
#pragma unroll
        for (int q = 63; q >= 0; --q) {
            int r = c * 64 + q;
            if (r < TT - 1) {
                // byte hist[r][tag]: local dword q*16+(tag>>2)
                unsigned int d = __shfl(dw[q >> 2], ((q & 3) << 4) + (tag >> 2));
                int pv = (int)((d >> ((tag & 3) << 3)) & 0xFFu);
                int m  = __shfl(mreg, q);
                tag = m ? pv : tag;
                if (l == 0) path[r] = tag;
            }
        }
    };

    loadChunk(7, dwA, mA);
    for (int c = 7; c >= 1; c -= 2) {
        loadChunk(c - 1, dwB, mB);
        procChunk(c, dwA, mA);
        if (c >= 2) loadChunk(c - 2, dwA, mA);
        procChunk(c - 1, dwB, mB);
    }

    __syncthreads();
#pragma unroll
    for (int cc = 0; cc < 8; ++cc)
        out[(size_t)b * TT + cc * 64 + l] = path[cc * 64 + l];
}

extern "C" void kernel_launch(void* const* d_in, const int* in_sizes, int n_in,
                              void* d_out, int out_size, void* d_ws, size_t ws_size,
                              hipStream_t stream) {
    const float* emissions = (const float*)d_in[0];
    const int* attn_mask   = (const int*)d_in[1];
    const float* start_t   = (const float*)d_in[2];
    const float* end_t     = (const float*)d_in[3];
    const float* trans     = (const float*)d_in[4];
    int* out = (int*)d_out;

    unsigned char* hist = (unsigned char*)d_ws;
    int* best_last = (int*)((char*)d_ws + (size_t)BB * TT * KK);

    viterbi_fwd<<<BB, KK, 0, stream>>>(emissions, attn_mask, start_t, end_t,
                                       trans, hist, best_last);
    viterbi_bt<<<BB, KK, 0, stream>>>(hist, attn_mask, best_last, out);
}